// Round 6
// baseline (3808.149 us; speedup 1.0000x reference)
//
#include <hip/hip_runtime.h>

#define NN 50000
#define NE 800000
#define IN_DIM 16
#define H 32
#define EDGE_DIM 4
#define T_STEPS 4
#define NPB 32
#define NBLK ((NN + NPB - 1) / NPB)   // 1563

// ---------------- embedding: h0 = inputs @ W_emb ----------------
__global__ __launch_bounds__(256) void embed_kernel(const float* __restrict__ inputs,
                                                    const float* __restrict__ W_emb,
                                                    float* __restrict__ h) {
    __shared__ float W[IN_DIM * H];
    for (int i = threadIdx.x; i < IN_DIM * H; i += 256) W[i] = W_emb[i];
    __syncthreads();
    int idx = blockIdx.x * 256 + threadIdx.x;
    if (idx >= NN * H) return;
    int n = idx >> 5, j = idx & 31;
    const float* xr = inputs + n * IN_DIM;
    float acc = 0.f;
#pragma unroll
    for (int k = 0; k < IN_DIM; ++k) acc += xr[k] * W[k * H + j];
    h[idx] = acc;
}

// ---------------- CSR build ----------------
__global__ __launch_bounds__(256) void hist_kernel(const int* __restrict__ dst, int* __restrict__ deg) {
    int e = blockIdx.x * 256 + threadIdx.x;
    if (e < NE) atomicAdd(&deg[dst[e]], 1);
}

#define SCAN_CHUNK 49
__global__ __launch_bounds__(1024) void scan_kernel(const int* __restrict__ deg, int* __restrict__ row_ptr) {
    __shared__ int part[1024];
    int tid = threadIdx.x;
    int start = tid * SCAN_CHUNK;
    int s = 0;
    for (int i = 0; i < SCAN_CHUNK; ++i) {
        int idx = start + i;
        if (idx < NN) s += deg[idx];
    }
    part[tid] = s;
    __syncthreads();
    for (int off = 1; off < 1024; off <<= 1) {
        int v = (tid >= off) ? part[tid - off] : 0;
        __syncthreads();
        part[tid] += v;
        __syncthreads();
    }
    int run = (tid == 0) ? 0 : part[tid - 1];
    for (int i = 0; i < SCAN_CHUNK; ++i) {
        int idx = start + i;
        if (idx <= NN) row_ptr[idx] = run;
        if (idx < NN) run += deg[idx];
    }
}

__global__ __launch_bounds__(256) void scatter_kernel(const int* __restrict__ src, const int* __restrict__ dst,
                                                      const int* __restrict__ row_ptr, int* __restrict__ cnt,
                                                      int* __restrict__ src_sorted, int* __restrict__ dst_sorted,
                                                      int* __restrict__ eid_sorted) {
    int e = blockIdx.x * 256 + threadIdx.x;
    if (e >= NE) return;
    int d = dst[e];
    int pos = row_ptr[d] + atomicAdd(&cnt[d], 1);
    src_sorted[pos] = src[e];
    dst_sorted[pos] = d;
    eid_sorted[pos] = e;
}

// ---------------- ef re-layout: ef_sorted[t][p][4] ----------------
__global__ __launch_bounds__(256) void ef_sort_kernel(const float* __restrict__ e_feats,
                                                      const int* __restrict__ eid_sorted,
                                                      float* __restrict__ ef_sorted) {
    int p = blockIdx.x * 256 + threadIdx.x;
    if (p >= NE) return;
    int e = eid_sorted[p];
    float buf[16];
    const float4* srcp = (const float4*)(e_feats + (size_t)e * (EDGE_DIM * T_STEPS));
#pragma unroll
    for (int q = 0; q < 4; ++q) {
        float4 v = srcp[q];
        buf[4 * q + 0] = v.x; buf[4 * q + 1] = v.y; buf[4 * q + 2] = v.z; buf[4 * q + 3] = v.w;
    }
#pragma unroll
    for (int t = 0; t < T_STEPS; ++t) {
        float4 o = make_float4(buf[t], buf[4 + t], buf[8 + t], buf[12 + t]);
        *(float4*)(ef_sorted + ((size_t)t * NE + p) * 4) = o;
    }
}

// ---------------- fused layer ----------------
// Edge phase: ONE edge per thread (acc[32] fits without spill); weights are
// lane-uniform loads -> scalar pipe; aggregation via LDS float atomics.
// Node phase: 8-way k-split + LDS atomic combine + fused rain projection.
__global__ __launch_bounds__(256) void layer_kernel(const float* __restrict__ h,
                                                    const float* __restrict__ ef_t,
                                                    const int* __restrict__ src_sorted,
                                                    const int* __restrict__ dst_sorted,
                                                    const int* __restrict__ row_ptr,
                                                    const float* __restrict__ rain0,
                                                    const float* __restrict__ We,
                                                    const float* __restrict__ Wn,
                                                    const float* __restrict__ Wrain,
                                                    float* __restrict__ hnew,
                                                    float* __restrict__ out,
                                                    int t, int last) {
    __shared__ float sagg[NPB * 33];
    __shared__ float shl[NPB * 33];

    int tid = threadIdx.x;
    int nb0 = blockIdx.x * NPB;
    int nEnd = min(nb0 + NPB, NN);
    int nloc = nEnd - nb0;

    for (int i = tid; i < NPB * 33; i += 256) sagg[i] = 0.f;
    for (int i = tid; i < nloc * H; i += 256) {
        int g = i >> 5, c = i & 31;
        shl[g * 33 + c] = h[(size_t)(nb0 + g) * H + c];
    }
    int e0 = row_ptr[nb0], e1 = row_ptr[nEnd];
    __syncthreads();

    // -------- edge phase: one edge per thread --------
    for (int p = e0 + tid; p < e1; p += 256) {
        int s = src_sorted[p];
        int dl = dst_sorted[p] - nb0;

        const float4* hr = (const float4*)(h + (size_t)s * H);
        float4 x0 = hr[0], x1 = hr[1], x2 = hr[2], x3 = hr[3];
        float4 x4 = hr[4], x5 = hr[5], x6 = hr[6], x7 = hr[7];
        float4 ev = *(const float4*)(ef_t + (size_t)p * 4);

        float acc[32];
#pragma unroll
        for (int j = 0; j < 32; ++j) acc[j] = 0.f;

#pragma unroll
        for (int kq = 0; kq < 9; ++kq) {
            float4 xv = (kq == 0) ? x0 : (kq == 1) ? x1 : (kq == 2) ? x2 : (kq == 3) ? x3
                      : (kq == 4) ? x4 : (kq == 5) ? x5 : (kq == 6) ? x6 : (kq == 7) ? x7 : ev;
#pragma unroll
            for (int kk = 0; kk < 4; ++kk) {
                int k = kq * 4 + kk;
                float xa = (kk == 0) ? xv.x : (kk == 1) ? xv.y : (kk == 2) ? xv.z : xv.w;
#pragma unroll
                for (int j = 0; j < 32; ++j) {
                    float w = We[k * 32 + j];   // lane-uniform -> scalar pipe
                    acc[j] = fmaf(xa, w, acc[j]);
                }
            }
        }
#pragma unroll
        for (int j = 0; j < 32; ++j)
            atomicAdd(&sagg[dl * 33 + j], fmaxf(acc[j], 0.f));
    }
    __syncthreads();

    // -------- node phase: 8-way k-split --------
    int nl = tid & 31;
    int q8 = tid >> 5;          // 0..7
    int n = nb0 + nl;
    bool on = (nl < nloc);
    float acc[32];
#pragma unroll
    for (int j = 0; j < 32; ++j) acc[j] = 0.f;
    if (on) {
        int k0 = q8 * 8;
#pragma unroll
        for (int kk = 0; kk < 8; ++kk) {
            int k = k0 + kk;
            float xk = (k < 32) ? shl[nl * 33 + k] : sagg[nl * 33 + (k - 32)];
            const float4* wr = (const float4*)(Wn + (size_t)k * 32);
#pragma unroll
            for (int j4 = 0; j4 < 8; ++j4) {
                float4 w = wr[j4];
                acc[4 * j4 + 0] = fmaf(xk, w.x, acc[4 * j4 + 0]);
                acc[4 * j4 + 1] = fmaf(xk, w.y, acc[4 * j4 + 1]);
                acc[4 * j4 + 2] = fmaf(xk, w.z, acc[4 * j4 + 2]);
                acc[4 * j4 + 3] = fmaf(xk, w.w, acc[4 * j4 + 3]);
            }
        }
        if (q8 == 7) {
            float rain = rain0[(size_t)n * T_STEPS + t];
            const float4* wr = (const float4*)(Wn + (size_t)64 * 32);
#pragma unroll
            for (int j4 = 0; j4 < 8; ++j4) {
                float4 w = wr[j4];
                acc[4 * j4 + 0] = fmaf(rain, w.x, acc[4 * j4 + 0]);
                acc[4 * j4 + 1] = fmaf(rain, w.y, acc[4 * j4 + 1]);
                acc[4 * j4 + 2] = fmaf(rain, w.z, acc[4 * j4 + 2]);
                acc[4 * j4 + 3] = fmaf(rain, w.w, acc[4 * j4 + 3]);
            }
        }
    }
    __syncthreads();
    // reuse shl as output accumulator
    for (int i = tid; i < NPB * 33; i += 256) shl[i] = 0.f;
    __syncthreads();
    if (on) {
#pragma unroll
        for (int j = 0; j < 32; ++j) atomicAdd(&shl[nl * 33 + j], acc[j]);
    }
    __syncthreads();
    if (tid < nloc) {
        int nn = nb0 + tid;
        float r = 0.f;
        float4* hw = (float4*)(hnew + (size_t)nn * H);
#pragma unroll
        for (int j4 = 0; j4 < 8; ++j4) {
            float4 v;
            v.x = fmaxf(shl[tid * 33 + 4 * j4 + 0], 0.f);
            v.y = fmaxf(shl[tid * 33 + 4 * j4 + 1], 0.f);
            v.z = fmaxf(shl[tid * 33 + 4 * j4 + 2], 0.f);
            v.w = fmaxf(shl[tid * 33 + 4 * j4 + 3], 0.f);
            hw[j4] = v;
            float4 wr = *(const float4*)(Wrain + 4 * j4);
            r += v.x * wr.x + v.y * wr.y + v.z * wr.z + v.w * wr.w;
        }
        if (last) out[(size_t)nn * T_STEPS + t] = r;
    }
}

extern "C" void kernel_launch(void* const* d_in, const int* in_sizes, int n_in,
                              void* d_out, int out_size, void* d_ws, size_t ws_size,
                              hipStream_t stream) {
    const float* inputs     = (const float*)d_in[0];
    const float* e_feats    = (const float*)d_in[1];
    const float* rain0      = (const float*)d_in[2];
    const float* W_emb      = (const float*)d_in[3];
    const float* W_edge_in  = (const float*)d_in[4];
    const float* W_node_in  = (const float*)d_in[5];
    const float* W_edge_out = (const float*)d_in[6];
    const float* W_node_out = (const float*)d_in[7];
    const float* W_rain     = (const float*)d_in[8];
    const int*   src        = (const int*)d_in[9];
    const int*   dst        = (const int*)d_in[10];
    float* out = (float*)d_out;

    // workspace layout (~74 MB)
    size_t fH = (size_t)NN * H;
    size_t fE = (size_t)NE * 4;
    float* h_a       = (float*)d_ws;
    float* h_b       = h_a + fH;
    float* ef_sorted = h_b + fH;                                   // T * NE * 4 floats
    int* row_ptr     = (int*)(ef_sorted + (size_t)T_STEPS * fE);   // NN+1
    int* deg         = row_ptr + (NN + 1);                         // NN
    int* cnt         = deg + NN;                                   // NN
    int* src_sorted  = cnt + NN;                                   // NE
    int* dst_sorted  = src_sorted + NE;                            // NE
    int* eid_sorted  = dst_sorted + NE;                            // NE

    embed_kernel<<<(NN * H + 255) / 256, 256, 0, stream>>>(inputs, W_emb, h_a);

    // CSR build
    hipMemsetAsync(deg, 0, (size_t)2 * NN * sizeof(int), stream);  // deg + cnt contiguous
    hist_kernel<<<(NE + 255) / 256, 256, 0, stream>>>(dst, deg);
    scan_kernel<<<1, 1024, 0, stream>>>(deg, row_ptr);
    scatter_kernel<<<(NE + 255) / 256, 256, 0, stream>>>(src, dst, row_ptr, cnt,
                                                         src_sorted, dst_sorted, eid_sorted);
    ef_sort_kernel<<<(NE + 255) / 256, 256, 0, stream>>>(e_feats, eid_sorted, ef_sorted);

    float* hc = h_a;
    float* hn = h_b;
    for (int t = 0; t < T_STEPS; ++t) {
        const float* ef_t = ef_sorted + (size_t)t * fE;
        for (int s = 0; s < 3; ++s) {
            const float* We = (s < 2) ? (W_edge_in + (size_t)s * 36 * H) : W_edge_out;
            const float* Wn = (s < 2) ? (W_node_in + (size_t)s * 65 * H) : W_node_out;
            layer_kernel<<<NBLK, 256, 0, stream>>>(hc, ef_t, src_sorted, dst_sorted, row_ptr, rain0,
                                                   We, Wn, W_rain, hn, out, t, (s == 2) ? 1 : 0);
            float* tmp = hc; hc = hn; hn = tmp;
        }
    }
}

// Round 7
// 962.107 us; speedup vs baseline: 3.9581x; 3.9581x over previous
//
#include <hip/hip_runtime.h>

#define NN 50000
#define NE 800000
#define IN_DIM 16
#define H 32
#define EDGE_DIM 4
#define T_STEPS 4
#define NPB 32
#define NBLK ((NN + NPB - 1) / NPB)   // 1563

// ---------------- embedding: h0 = inputs @ W_emb ----------------
__global__ __launch_bounds__(256) void embed_kernel(const float* __restrict__ inputs,
                                                    const float* __restrict__ W_emb,
                                                    float* __restrict__ h) {
    __shared__ float W[IN_DIM * H];
    for (int i = threadIdx.x; i < IN_DIM * H; i += 256) W[i] = W_emb[i];
    __syncthreads();
    int idx = blockIdx.x * 256 + threadIdx.x;
    if (idx >= NN * H) return;
    int n = idx >> 5, j = idx & 31;
    const float* xr = inputs + n * IN_DIM;
    float acc = 0.f;
#pragma unroll
    for (int k = 0; k < IN_DIM; ++k) acc += xr[k] * W[k * H + j];
    h[idx] = acc;
}

// ---------------- CSR build ----------------
__global__ __launch_bounds__(256) void hist_kernel(const int* __restrict__ dst, int* __restrict__ deg) {
    int e = blockIdx.x * 256 + threadIdx.x;
    if (e < NE) atomicAdd(&deg[dst[e]], 1);
}

#define SCAN_CHUNK 49
__global__ __launch_bounds__(1024) void scan_kernel(const int* __restrict__ deg, int* __restrict__ row_ptr) {
    __shared__ int part[1024];
    int tid = threadIdx.x;
    int start = tid * SCAN_CHUNK;
    int s = 0;
    for (int i = 0; i < SCAN_CHUNK; ++i) {
        int idx = start + i;
        if (idx < NN) s += deg[idx];
    }
    part[tid] = s;
    __syncthreads();
    for (int off = 1; off < 1024; off <<= 1) {
        int v = (tid >= off) ? part[tid - off] : 0;
        __syncthreads();
        part[tid] += v;
        __syncthreads();
    }
    int run = (tid == 0) ? 0 : part[tid - 1];
    for (int i = 0; i < SCAN_CHUNK; ++i) {
        int idx = start + i;
        if (idx <= NN) row_ptr[idx] = run;
        if (idx < NN) run += deg[idx];
    }
}

__global__ __launch_bounds__(256) void scatter_kernel(const int* __restrict__ src, const int* __restrict__ dst,
                                                      const int* __restrict__ row_ptr, int* __restrict__ cnt,
                                                      int* __restrict__ src_sorted, int* __restrict__ eid_sorted) {
    int e = blockIdx.x * 256 + threadIdx.x;
    if (e >= NE) return;
    int d = dst[e];
    int pos = row_ptr[d] + atomicAdd(&cnt[d], 1);
    src_sorted[pos] = src[e];
    eid_sorted[pos] = e;
}

// ---------------- ef re-layout: ef_sorted[t][p][4] ----------------
__global__ __launch_bounds__(256) void ef_sort_kernel(const float* __restrict__ e_feats,
                                                      const int* __restrict__ eid_sorted,
                                                      float* __restrict__ ef_sorted) {
    int p = blockIdx.x * 256 + threadIdx.x;
    if (p >= NE) return;
    int e = eid_sorted[p];
    float buf[16];
    const float4* srcp = (const float4*)(e_feats + (size_t)e * (EDGE_DIM * T_STEPS));
#pragma unroll
    for (int q = 0; q < 4; ++q) {
        float4 v = srcp[q];
        buf[4 * q + 0] = v.x; buf[4 * q + 1] = v.y; buf[4 * q + 2] = v.z; buf[4 * q + 3] = v.w;
    }
#pragma unroll
    for (int t = 0; t < T_STEPS; ++t) {
        float4 o = make_float4(buf[t], buf[4 + t], buf[8 + t], buf[12 + t]);
        *(float4*)(ef_sorted + ((size_t)t * NE + p) * 4) = o;
    }
}

// ---------------- fused layer ----------------
// Edge GEMM: lane = edge; x staged transposed in LDS (XT[k][e], pad 257);
// We rows stream through SGPRs (2 rows/iter, lane-uniform loads, unroll 1).
// Messages written back into own XT column; register segmented-sum per
// (node, channel-quad) thread. Node phase: thread owns (node, channel-quad).
__global__ __launch_bounds__(256) void layer_kernel(const float* __restrict__ h,
                                                    const float* __restrict__ ef_t,
                                                    const int* __restrict__ src_sorted,
                                                    const int* __restrict__ row_ptr,
                                                    const float* __restrict__ rain0,
                                                    const float* __restrict__ We,
                                                    const float* __restrict__ Wn,
                                                    const float* __restrict__ Wrain,
                                                    float* __restrict__ hnew,
                                                    float* __restrict__ out,
                                                    int t, int last) {
    __shared__ float XT[32 * 257];      // x transposed [k][edge], then msg [c][edge]
    __shared__ float shl[NPB * 33];     // own nodes' h
    __shared__ float sagg[NPB * 33];    // aggregated messages
    __shared__ float srain[NPB];
    __shared__ int srp[NPB + 1];

    int tid = threadIdx.x;
    int nb0 = blockIdx.x * NPB;
    int nEnd = min(nb0 + NPB, NN);
    int nloc = nEnd - nb0;

    if (tid <= nloc) srp[tid] = row_ptr[nb0 + tid];
    for (int i = tid; i < nloc * H; i += 256) {
        int g = i >> 5, c = i & 31;
        shl[g * 33 + c] = h[(size_t)(nb0 + g) * H + c];
    }
    if (tid < NPB) srain[tid] = 0.f;
    __syncthreads();
    int e0 = srp[0], e1 = srp[nloc];

    // segmented-sum ownership: thread (sg, sl) owns node sg, channels sl*4..+3
    int sg = tid >> 3, sl = tid & 7;
    int arb = (sg < nloc) ? srp[sg] : 0;
    int are = (sg < nloc) ? srp[sg + 1] : 0;
    float4 aggv = make_float4(0.f, 0.f, 0.f, 0.f);

    for (int cb = e0; cb < e1; cb += 256) {
        int p = cb + tid;
        bool act = (p < e1);
        float4 ev = make_float4(0.f, 0.f, 0.f, 0.f);
        if (act) {
            int s = src_sorted[p];
            const float4* hr = (const float4*)(h + (size_t)s * H);
#pragma unroll
            for (int q = 0; q < 8; ++q) {
                float4 v = hr[q];
                XT[(4 * q + 0) * 257 + tid] = v.x;
                XT[(4 * q + 1) * 257 + tid] = v.y;
                XT[(4 * q + 2) * 257 + tid] = v.z;
                XT[(4 * q + 3) * 257 + tid] = v.w;
            }
            ev = *(const float4*)(ef_t + (size_t)p * 4);
        }
        __syncthreads();
        if (act) {
            float acc[32];
#pragma unroll
            for (int j = 0; j < 32; ++j) acc[j] = 0.f;
            // k-loop NOT unrolled: per iter only 64 lane-uniform We scalars live -> SGPRs
#pragma unroll 1
            for (int k = 0; k < 32; k += 2) {
                float xa = XT[k * 257 + tid];
                float xb = XT[(k + 1) * 257 + tid];
                const float* w0 = &We[k * 32];
#pragma unroll
                for (int j = 0; j < 32; ++j) acc[j] = fmaf(xa, w0[j], acc[j]);
#pragma unroll
                for (int j = 0; j < 32; ++j) acc[j] = fmaf(xb, w0[32 + j], acc[j]);
            }
            // ef tail (k = 32..35), x from registers
#pragma unroll
            for (int j = 0; j < 32; ++j) acc[j] = fmaf(ev.x, We[32 * 32 + j], acc[j]);
#pragma unroll
            for (int j = 0; j < 32; ++j) acc[j] = fmaf(ev.y, We[33 * 32 + j], acc[j]);
#pragma unroll
            for (int j = 0; j < 32; ++j) acc[j] = fmaf(ev.z, We[34 * 32 + j], acc[j]);
#pragma unroll
            for (int j = 0; j < 32; ++j) acc[j] = fmaf(ev.w, We[35 * 32 + j], acc[j]);
            // relu + write message into own column (no cross-lane hazard)
#pragma unroll
            for (int c = 0; c < 32; ++c) XT[c * 257 + tid] = fmaxf(acc[c], 0.f);
        }
        __syncthreads();
        // register segmented sum over this chunk
        {
            int lo = max(arb, cb), hi = min(are, cb + 256);
            for (int p2 = lo; p2 < hi; ++p2) {
                int e = p2 - cb;
                aggv.x += XT[(sl * 4 + 0) * 257 + e];
                aggv.y += XT[(sl * 4 + 1) * 257 + e];
                aggv.z += XT[(sl * 4 + 2) * 257 + e];
                aggv.w += XT[(sl * 4 + 3) * 257 + e];
            }
        }
        __syncthreads();
    }
    if (sg < nloc) {
        sagg[sg * 33 + sl * 4 + 0] = aggv.x;
        sagg[sg * 33 + sl * 4 + 1] = aggv.y;
        sagg[sg * 33 + sl * 4 + 2] = aggv.z;
        sagg[sg * 33 + sl * 4 + 3] = aggv.w;
    }
    __syncthreads();

    // ---- node phase: thread (nl, cq) -> node nl, channels cq*4..+3 (exclusive) ----
    int nl = tid >> 3, cq = tid & 7;
    if (nl < nloc) {
        int n = nb0 + nl;
        float4 a = make_float4(0.f, 0.f, 0.f, 0.f);
#pragma unroll 8
        for (int k = 0; k < 32; ++k) {
            float xk = shl[nl * 33 + k];
            float4 w = *(const float4*)(Wn + (size_t)k * 32 + cq * 4);
            a.x = fmaf(xk, w.x, a.x); a.y = fmaf(xk, w.y, a.y);
            a.z = fmaf(xk, w.z, a.z); a.w = fmaf(xk, w.w, a.w);
        }
#pragma unroll 8
        for (int k = 0; k < 32; ++k) {
            float xk = sagg[nl * 33 + k];
            float4 w = *(const float4*)(Wn + (size_t)(32 + k) * 32 + cq * 4);
            a.x = fmaf(xk, w.x, a.x); a.y = fmaf(xk, w.y, a.y);
            a.z = fmaf(xk, w.z, a.z); a.w = fmaf(xk, w.w, a.w);
        }
        {
            float rain = rain0[(size_t)n * T_STEPS + t];
            float4 w = *(const float4*)(Wn + (size_t)64 * 32 + cq * 4);
            a.x = fmaf(rain, w.x, a.x); a.y = fmaf(rain, w.y, a.y);
            a.z = fmaf(rain, w.z, a.z); a.w = fmaf(rain, w.w, a.w);
        }
        a.x = fmaxf(a.x, 0.f); a.y = fmaxf(a.y, 0.f);
        a.z = fmaxf(a.z, 0.f); a.w = fmaxf(a.w, 0.f);
        *(float4*)(hnew + (size_t)n * H + cq * 4) = a;
        if (last) {
            float4 w = *(const float4*)(Wrain + cq * 4);
            float rv = a.x * w.x + a.y * w.y + a.z * w.z + a.w * w.w;
            atomicAdd(&srain[nl], rv);
        }
    }
    if (last) {
        __syncthreads();
        if (tid < nloc) out[(size_t)(nb0 + tid) * T_STEPS + t] = srain[tid];
    }
}

extern "C" void kernel_launch(void* const* d_in, const int* in_sizes, int n_in,
                              void* d_out, int out_size, void* d_ws, size_t ws_size,
                              hipStream_t stream) {
    const float* inputs     = (const float*)d_in[0];
    const float* e_feats    = (const float*)d_in[1];
    const float* rain0      = (const float*)d_in[2];
    const float* W_emb      = (const float*)d_in[3];
    const float* W_edge_in  = (const float*)d_in[4];
    const float* W_node_in  = (const float*)d_in[5];
    const float* W_edge_out = (const float*)d_in[6];
    const float* W_node_out = (const float*)d_in[7];
    const float* W_rain     = (const float*)d_in[8];
    const int*   src        = (const int*)d_in[9];
    const int*   dst        = (const int*)d_in[10];
    float* out = (float*)d_out;

    // workspace layout (~71 MB)
    size_t fH = (size_t)NN * H;
    size_t fE = (size_t)NE * 4;
    float* h_a       = (float*)d_ws;
    float* h_b       = h_a + fH;
    float* ef_sorted = h_b + fH;                                   // T * NE * 4 floats
    int* row_ptr     = (int*)(ef_sorted + (size_t)T_STEPS * fE);   // NN+1
    int* deg         = row_ptr + (NN + 1);                         // NN
    int* cnt         = deg + NN;                                   // NN
    int* src_sorted  = cnt + NN;                                   // NE
    int* eid_sorted  = src_sorted + NE;                            // NE

    embed_kernel<<<(NN * H + 255) / 256, 256, 0, stream>>>(inputs, W_emb, h_a);

    // CSR build
    hipMemsetAsync(deg, 0, (size_t)2 * NN * sizeof(int), stream);  // deg + cnt contiguous
    hist_kernel<<<(NE + 255) / 256, 256, 0, stream>>>(dst, deg);
    scan_kernel<<<1, 1024, 0, stream>>>(deg, row_ptr);
    scatter_kernel<<<(NE + 255) / 256, 256, 0, stream>>>(src, dst, row_ptr, cnt,
                                                         src_sorted, eid_sorted);
    ef_sort_kernel<<<(NE + 255) / 256, 256, 0, stream>>>(e_feats, eid_sorted, ef_sorted);

    float* hc = h_a;
    float* hn = h_b;
    for (int t = 0; t < T_STEPS; ++t) {
        const float* ef_t = ef_sorted + (size_t)t * fE;
        for (int s = 0; s < 3; ++s) {
            const float* We = (s < 2) ? (W_edge_in + (size_t)s * 36 * H) : W_edge_out;
            const float* Wn = (s < 2) ? (W_node_in + (size_t)s * 65 * H) : W_node_out;
            layer_kernel<<<NBLK, 256, 0, stream>>>(hc, ef_t, src_sorted, row_ptr, rain0,
                                                   We, Wn, W_rain, hn, out, t, (s == 2) ? 1 : 0);
            float* tmp = hc; hc = hn; hn = tmp;
        }
    }
}

// Round 8
// 820.764 us; speedup vs baseline: 4.6398x; 1.1722x over previous
//
#include <hip/hip_runtime.h>
#include <cstdint>

#define NN 50000
#define NE 800000
#define IN_DIM 16
#define H 32
#define EDGE_DIM 4
#define T_STEPS 4
#define NPB 32
#define NBLK ((NN + NPB - 1) / NPB)   // 1563
#define SBLK 196                      // scan blocks (196*256 >= NN+1)

typedef __bf16 bf16x8 __attribute__((ext_vector_type(8)));
typedef float f32x4 __attribute__((ext_vector_type(4)));
typedef unsigned int u32x4 __attribute__((ext_vector_type(4)));

__device__ __forceinline__ uint32_t bf_rne1(float f) {
    uint32_t u = __float_as_uint(f);
    return (u + 0x7FFFu + ((u >> 16) & 1u)) >> 16;
}
__device__ __forceinline__ float bf2f(uint32_t h16) { return __uint_as_float(h16 << 16); }
__device__ __forceinline__ uint32_t bfpair(float a, float b) {
    return (bf_rne1(b) << 16) | bf_rne1(a);
}
__device__ __forceinline__ bf16x8 asbf(u32x4 u) { return __builtin_bit_cast(bf16x8, u); }
__device__ __forceinline__ f32x4 MFMA(bf16x8 a, bf16x8 b, f32x4 c) {
    return __builtin_amdgcn_mfma_f32_16x16x32_bf16(a, b, c, 0, 0, 0);
}

// ---------------- embedding: h0 = inputs @ W_emb (+ packed bf16 hi/lo) ----------------
__global__ __launch_bounds__(256) void embed_kernel(const float* __restrict__ inputs,
                                                    const float* __restrict__ W_emb,
                                                    float* __restrict__ h,
                                                    uint32_t* __restrict__ h_hi,
                                                    uint32_t* __restrict__ h_lo) {
    int idx = blockIdx.x * 256 + threadIdx.x;
    if (idx >= NN * 8) return;
    int n = idx >> 3, cq = idx & 7;
    const float* xr = inputs + (size_t)n * IN_DIM;
    float4 a = make_float4(0.f, 0.f, 0.f, 0.f);
#pragma unroll
    for (int k = 0; k < IN_DIM; ++k) {
        float xk = xr[k];
        float4 w = *(const float4*)(W_emb + k * 32 + cq * 4);
        a.x = fmaf(xk, w.x, a.x); a.y = fmaf(xk, w.y, a.y);
        a.z = fmaf(xk, w.z, a.z); a.w = fmaf(xk, w.w, a.w);
    }
    *(float4*)(h + (size_t)n * 32 + cq * 4) = a;
    uint32_t p0 = bfpair(a.x, a.y), p1 = bfpair(a.z, a.w);
    h_hi[(size_t)n * 16 + cq * 2] = p0;
    h_hi[(size_t)n * 16 + cq * 2 + 1] = p1;
    float r0 = a.x - bf2f(p0 & 0xFFFFu), r1 = a.y - bf2f(p0 >> 16);
    float r2 = a.z - bf2f(p1 & 0xFFFFu), r3 = a.w - bf2f(p1 >> 16);
    h_lo[(size_t)n * 16 + cq * 2] = bfpair(r0, r1);
    h_lo[(size_t)n * 16 + cq * 2 + 1] = bfpair(r2, r3);
}

// ---------------- CSR build ----------------
__global__ __launch_bounds__(256) void hist_kernel(const int* __restrict__ dst, int* __restrict__ deg) {
    int e = blockIdx.x * 256 + threadIdx.x;
    if (e < NE) atomicAdd(&deg[dst[e]], 1);
}

__global__ __launch_bounds__(256) void scan_part(const int* __restrict__ deg, int* __restrict__ bsum) {
    __shared__ int red[256];
    int i = blockIdx.x * 256 + threadIdx.x;
    red[threadIdx.x] = (i < NN) ? deg[i] : 0;
    __syncthreads();
    for (int off = 128; off > 0; off >>= 1) {
        if (threadIdx.x < off) red[threadIdx.x] += red[threadIdx.x + off];
        __syncthreads();
    }
    if (threadIdx.x == 0) bsum[blockIdx.x] = red[0];
}

__global__ __launch_bounds__(256) void scan_tops(const int* __restrict__ bsum, int* __restrict__ btop) {
    __shared__ int s[256];
    int tid = threadIdx.x;
    int v0 = (tid < SBLK) ? bsum[tid] : 0;
    s[tid] = v0;
    __syncthreads();
    for (int off = 1; off < 256; off <<= 1) {
        int v = (tid >= off) ? s[tid - off] : 0;
        __syncthreads();
        s[tid] += v;
        __syncthreads();
    }
    if (tid < SBLK) btop[tid] = s[tid] - v0;   // exclusive
}

__global__ __launch_bounds__(256) void scan_final(const int* __restrict__ deg,
                                                  const int* __restrict__ btop,
                                                  int* __restrict__ row_ptr) {
    __shared__ int s[256];
    int tid = threadIdx.x;
    int i = blockIdx.x * 256 + tid;
    int v0 = (i < NN) ? deg[i] : 0;
    s[tid] = v0;
    __syncthreads();
    for (int off = 1; off < 256; off <<= 1) {
        int v = (tid >= off) ? s[tid - off] : 0;
        __syncthreads();
        s[tid] += v;
        __syncthreads();
    }
    if (i <= NN) row_ptr[i] = btop[blockIdx.x] + s[tid] - v0;
}

__global__ __launch_bounds__(256) void scatter_kernel(const int* __restrict__ src, const int* __restrict__ dst,
                                                      const int* __restrict__ row_ptr, int* __restrict__ cnt,
                                                      int* __restrict__ src_sorted, int* __restrict__ eid_sorted) {
    int e = blockIdx.x * 256 + threadIdx.x;
    if (e >= NE) return;
    int d = dst[e];
    int pos = row_ptr[d] + atomicAdd(&cnt[d], 1);
    src_sorted[pos] = src[e];
    eid_sorted[pos] = e;
}

// ---------------- ef re-layout: packed bf16 hi/lo per t-plane ----------------
__global__ __launch_bounds__(256) void ef_sort_kernel(const float* __restrict__ e_feats,
                                                      const int* __restrict__ eid_sorted,
                                                      uint32_t* __restrict__ ef_hi,
                                                      uint32_t* __restrict__ ef_lo) {
    int p = blockIdx.x * 256 + threadIdx.x;
    if (p >= NE) return;
    int e = eid_sorted[p];
    float buf[16];
    const float4* srcp = (const float4*)(e_feats + (size_t)e * (EDGE_DIM * T_STEPS));
#pragma unroll
    for (int q = 0; q < 4; ++q) {
        float4 v = srcp[q];
        buf[4 * q + 0] = v.x; buf[4 * q + 1] = v.y; buf[4 * q + 2] = v.z; buf[4 * q + 3] = v.w;
    }
#pragma unroll
    for (int t = 0; t < T_STEPS; ++t) {
        float f0 = buf[t], f1 = buf[4 + t], f2 = buf[8 + t], f3 = buf[12 + t];
        uint32_t h0 = bfpair(f0, f1), h1 = bfpair(f2, f3);
        float r0 = f0 - bf2f(h0 & 0xFFFFu), r1 = f1 - bf2f(h0 >> 16);
        float r2 = f2 - bf2f(h1 & 0xFFFFu), r3 = f3 - bf2f(h1 >> 16);
        size_t base = ((size_t)t * NE + p) * 2;
        ef_hi[base] = h0; ef_hi[base + 1] = h1;
        ef_lo[base] = bfpair(r0, r1); ef_lo[base + 1] = bfpair(r2, r3);
    }
}

// ---------------- We -> B-fragment prep ----------------
// frag[mat][kstep][ntile][hilo][lane] : u32x4 (8 bf16)
// B elem j of lane l: k = kstep*32 + (j<4?0:16) + ((l>>4)&3)*4 + (j&3); col = ntile*16 + (l&15)
__global__ __launch_bounds__(256) void wefrag_kernel(const float* __restrict__ We_in,
                                                     const float* __restrict__ We_out,
                                                     u32x4* __restrict__ frag) {
    int idx = blockIdx.x * 256 + threadIdx.x;
    if (idx >= 3 * 2 * 2 * 2 * 64) return;
    int lane = idx & 63;
    int hl = (idx >> 6) & 1;
    int nt = (idx >> 7) & 1;
    int ks = (idx >> 8) & 1;
    int mat = idx >> 9;
    const float* W = (mat < 2) ? (We_in + (size_t)mat * 36 * 32) : We_out;
    int col = (lane & 15) + nt * 16;
    int kb = ks * 32 + ((lane >> 4) & 3) * 4;
    u32x4 o;
#pragma unroll
    for (int i = 0; i < 4; ++i) {
        int k0 = kb + (i >= 2 ? 16 : 0) + (i & 1) * 2;
        float v0 = (k0 < 36) ? W[(size_t)k0 * 32 + col] : 0.f;
        float v1 = (k0 + 1 < 36) ? W[(size_t)(k0 + 1) * 32 + col] : 0.f;
        if (hl) {
            v0 -= bf2f(bf_rne1(v0));
            v1 -= bf2f(bf_rne1(v1));
        }
        o[i] = bfpair(v0, v1);
    }
    frag[idx] = o;
}

// ---------------- fused layer: MFMA edge GEMM + LDS segsum + node update ----------------
__global__ __launch_bounds__(256) void layer_kernel(const float* __restrict__ h,
                                                    const uint32_t* __restrict__ h_hi,
                                                    const uint32_t* __restrict__ h_lo,
                                                    const uint32_t* __restrict__ efh,
                                                    const uint32_t* __restrict__ efl,
                                                    const int* __restrict__ src_sorted,
                                                    const int* __restrict__ row_ptr,
                                                    const float* __restrict__ rain0,
                                                    const u32x4* __restrict__ wfrag,
                                                    const float* __restrict__ Wn,
                                                    const float* __restrict__ Wrain,
                                                    float* __restrict__ hnew,
                                                    uint32_t* __restrict__ hn_hi,
                                                    uint32_t* __restrict__ hn_lo,
                                                    float* __restrict__ out,
                                                    int t, int last) {
    __shared__ float msgT[32 * 132];    // [ch][row-in-chunk], pad 132
    __shared__ float shl[NPB * 33];
    __shared__ float sagg[NPB * 33];
    __shared__ float srain[NPB];
    __shared__ int srp[NPB + 1];

    int tid = threadIdx.x;
    int nb0 = blockIdx.x * NPB;
    int nEnd = min(nb0 + NPB, NN);
    int nloc = nEnd - nb0;

    if (tid <= nloc) srp[tid] = row_ptr[nb0 + tid];
    for (int i = tid; i < nloc * 32; i += 256) {
        int g = i >> 5, c = i & 31;
        shl[g * 33 + c] = h[(size_t)(nb0 + g) * 32 + c];
    }
    if (tid < NPB) srain[tid] = 0.f;
    __syncthreads();
    int e0 = srp[0], e1 = srp[nloc];

    int lane = tid & 63, w = tid >> 6;
    int erow = lane & 15, kg = lane >> 4;

    // hoist B fragments (this layer's We) into registers
    u32x4 b[2][2][2];
#pragma unroll
    for (int ks = 0; ks < 2; ++ks)
#pragma unroll
        for (int nt = 0; nt < 2; ++nt)
#pragma unroll
            for (int hl = 0; hl < 2; ++hl)
                b[ks][nt][hl] = wfrag[((ks * 2 + nt) * 2 + hl) * 64 + lane];

    // segsum ownership: thread (sg, sl) -> node sg, channels sl*4..+3
    int sg = tid >> 3, sl = tid & 7;
    int arb = (sg < nloc) ? srp[sg] : 0;
    int are = (sg < nloc) ? srp[sg + 1] : 0;
    float4 aggv = make_float4(0.f, 0.f, 0.f, 0.f);

    for (int cb = e0; cb < e1; cb += 128) {
#pragma unroll
        for (int sub = 0; sub < 2; ++sub) {
            int tb = cb + sub * 64 + w * 16;
            int p = tb + erow;
            bool act = (p < e1);
            int s = act ? src_sorted[p] : 0;
            const uint2* hh = (const uint2*)h_hi + (size_t)s * 8;
            const uint2* hlp = (const uint2*)h_lo + (size_t)s * 8;
            uint2 A0 = hh[kg], A1 = hh[4 + kg];
            uint2 L0 = hlp[kg], L1 = hlp[4 + kg];
            u32x4 a0h = {A0.x, A0.y, A1.x, A1.y};
            u32x4 a0l = {L0.x, L0.y, L1.x, L1.y};
            uint2 E = (act && kg == 0) ? *((const uint2*)efh + (size_t)p) : make_uint2(0u, 0u);
            uint2 EL = (act && kg == 0) ? *((const uint2*)efl + (size_t)p) : make_uint2(0u, 0u);
            u32x4 a1h = {E.x, E.y, 0u, 0u};
            u32x4 a1l = {EL.x, EL.y, 0u, 0u};

            f32x4 c0 = {0.f, 0.f, 0.f, 0.f};
            f32x4 c1 = {0.f, 0.f, 0.f, 0.f};
            bf16x8 A0h = asbf(a0h), A0l = asbf(a0l), A1h = asbf(a1h), A1l = asbf(a1l);
            // hi*hi + hi*lo + lo*hi (lo*lo dropped, ~2^-18)
            c0 = MFMA(A0h, asbf(b[0][0][0]), c0);
            c0 = MFMA(A0h, asbf(b[0][0][1]), c0);
            c0 = MFMA(A0l, asbf(b[0][0][0]), c0);
            c0 = MFMA(A1h, asbf(b[1][0][0]), c0);
            c0 = MFMA(A1h, asbf(b[1][0][1]), c0);
            c0 = MFMA(A1l, asbf(b[1][0][0]), c0);
            c1 = MFMA(A0h, asbf(b[0][1][0]), c1);
            c1 = MFMA(A0h, asbf(b[0][1][1]), c1);
            c1 = MFMA(A0l, asbf(b[0][1][0]), c1);
            c1 = MFMA(A1h, asbf(b[1][1][0]), c1);
            c1 = MFMA(A1h, asbf(b[1][1][1]), c1);
            c1 = MFMA(A1l, asbf(b[1][1][0]), c1);

            // C/D: col = lane&15 (channel), row = kg*4 + reg (edge in tile)  [m89-verified]
            int r0 = (tb - cb) + kg * 4;
            float4 m0, m1;
            m0.x = fmaxf(c0[0], 0.f); m0.y = fmaxf(c0[1], 0.f);
            m0.z = fmaxf(c0[2], 0.f); m0.w = fmaxf(c0[3], 0.f);
            m1.x = fmaxf(c1[0], 0.f); m1.y = fmaxf(c1[1], 0.f);
            m1.z = fmaxf(c1[2], 0.f); m1.w = fmaxf(c1[3], 0.f);
            *(float4*)&msgT[erow * 132 + r0] = m0;
            *(float4*)&msgT[(16 + erow) * 132 + r0] = m1;
        }
        __syncthreads();
        // register segmented sum over this 128-edge chunk
        if (sg < nloc) {
            int lo = max(arb, cb), hi = min(are, cb + 128);
            for (int p2 = lo; p2 < hi; ++p2) {
                int e = p2 - cb;
                aggv.x += msgT[(sl * 4 + 0) * 132 + e];
                aggv.y += msgT[(sl * 4 + 1) * 132 + e];
                aggv.z += msgT[(sl * 4 + 2) * 132 + e];
                aggv.w += msgT[(sl * 4 + 3) * 132 + e];
            }
        }
        __syncthreads();
    }
    if (sg < nloc) {
        sagg[sg * 33 + sl * 4 + 0] = aggv.x;
        sagg[sg * 33 + sl * 4 + 1] = aggv.y;
        sagg[sg * 33 + sl * 4 + 2] = aggv.z;
        sagg[sg * 33 + sl * 4 + 3] = aggv.w;
    }
    __syncthreads();

    // ---- node phase: thread (nl, cq) -> node nl, channels cq*4..+3 (exclusive) ----
    int nl = tid >> 3, cq = tid & 7;
    if (nl < nloc) {
        int n = nb0 + nl;
        float4 a = make_float4(0.f, 0.f, 0.f, 0.f);
#pragma unroll 8
        for (int k = 0; k < 32; ++k) {
            float xk = shl[nl * 33 + k];
            float4 wv = *(const float4*)(Wn + (size_t)k * 32 + cq * 4);
            a.x = fmaf(xk, wv.x, a.x); a.y = fmaf(xk, wv.y, a.y);
            a.z = fmaf(xk, wv.z, a.z); a.w = fmaf(xk, wv.w, a.w);
        }
#pragma unroll 8
        for (int k = 0; k < 32; ++k) {
            float xk = sagg[nl * 33 + k];
            float4 wv = *(const float4*)(Wn + (size_t)(32 + k) * 32 + cq * 4);
            a.x = fmaf(xk, wv.x, a.x); a.y = fmaf(xk, wv.y, a.y);
            a.z = fmaf(xk, wv.z, a.z); a.w = fmaf(xk, wv.w, a.w);
        }
        {
            float rain = rain0[(size_t)n * T_STEPS + t];
            float4 wv = *(const float4*)(Wn + (size_t)64 * 32 + cq * 4);
            a.x = fmaf(rain, wv.x, a.x); a.y = fmaf(rain, wv.y, a.y);
            a.z = fmaf(rain, wv.z, a.z); a.w = fmaf(rain, wv.w, a.w);
        }
        a.x = fmaxf(a.x, 0.f); a.y = fmaxf(a.y, 0.f);
        a.z = fmaxf(a.z, 0.f); a.w = fmaxf(a.w, 0.f);
        *(float4*)(hnew + (size_t)n * 32 + cq * 4) = a;
        uint32_t p0 = bfpair(a.x, a.y), p1 = bfpair(a.z, a.w);
        hn_hi[(size_t)n * 16 + cq * 2] = p0;
        hn_hi[(size_t)n * 16 + cq * 2 + 1] = p1;
        float r0 = a.x - bf2f(p0 & 0xFFFFu), r1 = a.y - bf2f(p0 >> 16);
        float r2 = a.z - bf2f(p1 & 0xFFFFu), r3 = a.w - bf2f(p1 >> 16);
        hn_lo[(size_t)n * 16 + cq * 2] = bfpair(r0, r1);
        hn_lo[(size_t)n * 16 + cq * 2 + 1] = bfpair(r2, r3);
        if (last) {
            float4 wr = *(const float4*)(Wrain + cq * 4);
            float rv = a.x * wr.x + a.y * wr.y + a.z * wr.z + a.w * wr.w;
            atomicAdd(&srain[nl], rv);
        }
    }
    if (last) {
        __syncthreads();
        if (tid < nloc) out[(size_t)(nb0 + tid) * T_STEPS + t] = srain[tid];
    }
}

extern "C" void kernel_launch(void* const* d_in, const int* in_sizes, int n_in,
                              void* d_out, int out_size, void* d_ws, size_t ws_size,
                              hipStream_t stream) {
    const float* inputs     = (const float*)d_in[0];
    const float* e_feats    = (const float*)d_in[1];
    const float* rain0      = (const float*)d_in[2];
    const float* W_emb      = (const float*)d_in[3];
    const float* W_edge_in  = (const float*)d_in[4];
    const float* W_node_in  = (const float*)d_in[5];
    const float* W_edge_out = (const float*)d_in[6];
    const float* W_node_out = (const float*)d_in[7];
    const float* W_rain     = (const float*)d_in[8];
    const int*   src        = (const int*)d_in[9];
    const int*   dst        = (const int*)d_in[10];
    float* out = (float*)d_out;

    // workspace layout (~84 MB)
    float* h_a = (float*)d_ws;                                   // NN*32
    float* h_b = h_a + (size_t)NN * 32;                          // NN*32
    uint32_t* hhi_a = (uint32_t*)(h_b + (size_t)NN * 32);        // NN*16
    uint32_t* hlo_a = hhi_a + (size_t)NN * 16;
    uint32_t* hhi_b = hlo_a + (size_t)NN * 16;
    uint32_t* hlo_b = hhi_b + (size_t)NN * 16;
    uint32_t* efh   = hlo_b + (size_t)NN * 16;                   // T*NE*2
    uint32_t* efl   = efh + (size_t)T_STEPS * NE * 2;            // T*NE*2
    u32x4* wfrag    = (u32x4*)(efl + (size_t)T_STEPS * NE * 2);  // 1536
    int* row_ptr    = (int*)(wfrag + 1536);                      // NN+1
    int* deg        = row_ptr + (NN + 1);                        // NN
    int* cnt        = deg + NN;                                  // NN
    int* src_sorted = cnt + NN;                                  // NE
    int* eid_sorted = src_sorted + NE;                           // NE
    int* bsum       = eid_sorted + NE;                           // SBLK
    int* btop       = bsum + SBLK;                               // SBLK

    embed_kernel<<<(NN * 8 + 255) / 256, 256, 0, stream>>>(inputs, W_emb, h_a, hhi_a, hlo_a);

    // CSR build (hierarchical scan)
    hipMemsetAsync(deg, 0, (size_t)2 * NN * sizeof(int), stream);  // deg + cnt contiguous
    hist_kernel<<<(NE + 255) / 256, 256, 0, stream>>>(dst, deg);
    scan_part<<<SBLK, 256, 0, stream>>>(deg, bsum);
    scan_tops<<<1, 256, 0, stream>>>(bsum, btop);
    scan_final<<<SBLK, 256, 0, stream>>>(deg, btop, row_ptr);
    scatter_kernel<<<(NE + 255) / 256, 256, 0, stream>>>(src, dst, row_ptr, cnt, src_sorted, eid_sorted);
    ef_sort_kernel<<<(NE + 255) / 256, 256, 0, stream>>>(e_feats, eid_sorted, efh, efl);
    wefrag_kernel<<<6, 256, 0, stream>>>(W_edge_in, W_edge_out, wfrag);

    float* hc = h_a;  float* hn = h_b;
    uint32_t* hic = hhi_a; uint32_t* hil = hlo_a;
    uint32_t* hnc = hhi_b; uint32_t* hnl = hlo_b;
    for (int t = 0; t < T_STEPS; ++t) {
        const uint32_t* efh_t = efh + (size_t)t * NE * 2;
        const uint32_t* efl_t = efl + (size_t)t * NE * 2;
        for (int s = 0; s < 3; ++s) {
            int mat = (s < 2) ? s : 2;
            const float* Wn = (s < 2) ? (W_node_in + (size_t)s * 65 * 32) : W_node_out;
            layer_kernel<<<NBLK, 256, 0, stream>>>(hc, hic, hil, efh_t, efl_t,
                                                   src_sorted, row_ptr, rain0,
                                                   wfrag + (size_t)mat * 512, Wn, W_rain,
                                                   hn, hnc, hnl, out, t, (s == 2) ? 1 : 0);
            float* tf = hc; hc = hn; hn = tf;
            uint32_t* t1 = hic; hic = hnc; hnc = t1;
            uint32_t* t2 = hil; hil = hnl; hnl = t2;
        }
    }
}

// Round 9
// 804.997 us; speedup vs baseline: 4.7306x; 1.0196x over previous
//
#include <hip/hip_runtime.h>
#include <cstdint>

#define NN 50000
#define NE 800000
#define IN_DIM 16
#define H 32
#define EDGE_DIM 4
#define T_STEPS 4
#define NPB 32
#define NBLK ((NN + NPB - 1) / NPB)   // 1563
#define SBLK 196                      // scan blocks (196*256 >= NN+1)
#define CHUNK 256

typedef __bf16 bf16x8 __attribute__((ext_vector_type(8)));
typedef float f32x4 __attribute__((ext_vector_type(4)));
typedef unsigned int u32x4 __attribute__((ext_vector_type(4)));

__device__ __forceinline__ uint32_t bf_rne1(float f) {
    uint32_t u = __float_as_uint(f);
    return (u + 0x7FFFu + ((u >> 16) & 1u)) >> 16;
}
__device__ __forceinline__ float bf2f(uint32_t h16) { return __uint_as_float(h16 << 16); }
__device__ __forceinline__ uint32_t bfpair(float a, float b) {
    return (bf_rne1(b) << 16) | bf_rne1(a);
}
__device__ __forceinline__ bf16x8 asbf(u32x4 u) { return __builtin_bit_cast(bf16x8, u); }
__device__ __forceinline__ f32x4 MFMA(bf16x8 a, bf16x8 b, f32x4 c) {
    return __builtin_amdgcn_mfma_f32_16x16x32_bf16(a, b, c, 0, 0, 0);
}

// ---------------- embedding: h0 = inputs @ W_emb (+ packed bf16 hi/lo) ----------------
__global__ __launch_bounds__(256) void embed_kernel(const float* __restrict__ inputs,
                                                    const float* __restrict__ W_emb,
                                                    float* __restrict__ h,
                                                    uint32_t* __restrict__ h_hi,
                                                    uint32_t* __restrict__ h_lo) {
    int idx = blockIdx.x * 256 + threadIdx.x;
    if (idx >= NN * 8) return;
    int n = idx >> 3, cq = idx & 7;
    const float* xr = inputs + (size_t)n * IN_DIM;
    float4 a = make_float4(0.f, 0.f, 0.f, 0.f);
#pragma unroll
    for (int k = 0; k < IN_DIM; ++k) {
        float xk = xr[k];
        float4 w = *(const float4*)(W_emb + k * 32 + cq * 4);
        a.x = fmaf(xk, w.x, a.x); a.y = fmaf(xk, w.y, a.y);
        a.z = fmaf(xk, w.z, a.z); a.w = fmaf(xk, w.w, a.w);
    }
    *(float4*)(h + (size_t)n * 32 + cq * 4) = a;
    uint32_t p0 = bfpair(a.x, a.y), p1 = bfpair(a.z, a.w);
    h_hi[(size_t)n * 16 + cq * 2] = p0;
    h_hi[(size_t)n * 16 + cq * 2 + 1] = p1;
    float r0 = a.x - bf2f(p0 & 0xFFFFu), r1 = a.y - bf2f(p0 >> 16);
    float r2 = a.z - bf2f(p1 & 0xFFFFu), r3 = a.w - bf2f(p1 >> 16);
    h_lo[(size_t)n * 16 + cq * 2] = bfpair(r0, r1);
    h_lo[(size_t)n * 16 + cq * 2 + 1] = bfpair(r2, r3);
}

// ---------------- CSR build ----------------
__global__ __launch_bounds__(256) void hist_kernel(const int* __restrict__ dst, int* __restrict__ deg) {
    int e = blockIdx.x * 256 + threadIdx.x;
    if (e < NE) atomicAdd(&deg[dst[e]], 1);
}

__global__ __launch_bounds__(256) void scan_part(const int* __restrict__ deg, int* __restrict__ bsum) {
    __shared__ int red[256];
    int i = blockIdx.x * 256 + threadIdx.x;
    red[threadIdx.x] = (i < NN) ? deg[i] : 0;
    __syncthreads();
    for (int off = 128; off > 0; off >>= 1) {
        if (threadIdx.x < off) red[threadIdx.x] += red[threadIdx.x + off];
        __syncthreads();
    }
    if (threadIdx.x == 0) bsum[blockIdx.x] = red[0];
}

__global__ __launch_bounds__(256) void scan_tops(const int* __restrict__ bsum, int* __restrict__ btop) {
    __shared__ int s[256];
    int tid = threadIdx.x;
    int v0 = (tid < SBLK) ? bsum[tid] : 0;
    s[tid] = v0;
    __syncthreads();
    for (int off = 1; off < 256; off <<= 1) {
        int v = (tid >= off) ? s[tid - off] : 0;
        __syncthreads();
        s[tid] += v;
        __syncthreads();
    }
    if (tid < SBLK) btop[tid] = s[tid] - v0;   // exclusive
}

__global__ __launch_bounds__(256) void scan_final(const int* __restrict__ deg,
                                                  const int* __restrict__ btop,
                                                  int* __restrict__ row_ptr) {
    __shared__ int s[256];
    int tid = threadIdx.x;
    int i = blockIdx.x * 256 + tid;
    int v0 = (i < NN) ? deg[i] : 0;
    s[tid] = v0;
    __syncthreads();
    for (int off = 1; off < 256; off <<= 1) {
        int v = (tid >= off) ? s[tid - off] : 0;
        __syncthreads();
        s[tid] += v;
        __syncthreads();
    }
    if (i <= NN) row_ptr[i] = btop[blockIdx.x] + s[tid] - v0;
}

// one 8B store per edge (halves random-write granules vs two 4B stores)
__global__ __launch_bounds__(256) void scatter_kernel(const int* __restrict__ src, const int* __restrict__ dst,
                                                      const int* __restrict__ row_ptr, int* __restrict__ cnt,
                                                      uint2* __restrict__ se_sorted) {
    int e = blockIdx.x * 256 + threadIdx.x;
    if (e >= NE) return;
    int d = dst[e];
    int pos = row_ptr[d] + atomicAdd(&cnt[d], 1);
    se_sorted[pos] = make_uint2((unsigned)src[e], (unsigned)e);
}

// ---------------- ef re-layout: packed {hi0,hi1,lo0,lo1} per (t,p) ----------------
__global__ __launch_bounds__(256) void ef_sort_kernel(const float* __restrict__ e_feats,
                                                      const uint2* __restrict__ se_sorted,
                                                      u32x4* __restrict__ ef4) {
    int p = blockIdx.x * 256 + threadIdx.x;
    if (p >= NE) return;
    int e = (int)se_sorted[p].y;
    float buf[16];
    const float4* srcp = (const float4*)(e_feats + (size_t)e * (EDGE_DIM * T_STEPS));
#pragma unroll
    for (int q = 0; q < 4; ++q) {
        float4 v = srcp[q];
        buf[4 * q + 0] = v.x; buf[4 * q + 1] = v.y; buf[4 * q + 2] = v.z; buf[4 * q + 3] = v.w;
    }
#pragma unroll
    for (int t = 0; t < T_STEPS; ++t) {
        float f0 = buf[t], f1 = buf[4 + t], f2 = buf[8 + t], f3 = buf[12 + t];
        uint32_t h0 = bfpair(f0, f1), h1 = bfpair(f2, f3);
        float r0 = f0 - bf2f(h0 & 0xFFFFu), r1 = f1 - bf2f(h0 >> 16);
        float r2 = f2 - bf2f(h1 & 0xFFFFu), r3 = f3 - bf2f(h1 >> 16);
        u32x4 o = {h0, h1, bfpair(r0, r1), bfpair(r2, r3)};
        ef4[(size_t)t * NE + p] = o;
    }
}

// ---------------- We -> B-fragment prep (unchanged layout, r7-verified) ----------------
__global__ __launch_bounds__(256) void wefrag_kernel(const float* __restrict__ We_in,
                                                     const float* __restrict__ We_out,
                                                     u32x4* __restrict__ frag) {
    int idx = blockIdx.x * 256 + threadIdx.x;
    if (idx >= 3 * 2 * 2 * 2 * 64) return;
    int lane = idx & 63;
    int hl = (idx >> 6) & 1;
    int nt = (idx >> 7) & 1;
    int ks = (idx >> 8) & 1;
    int mat = idx >> 9;
    const float* W = (mat < 2) ? (We_in + (size_t)mat * 36 * 32) : We_out;
    int col = (lane & 15) + nt * 16;
    int kb = ks * 32 + ((lane >> 4) & 3) * 4;
    u32x4 o;
#pragma unroll
    for (int i = 0; i < 4; ++i) {
        int k0 = kb + (i >= 2 ? 16 : 0) + (i & 1) * 2;
        float v0 = (k0 < 36) ? W[(size_t)k0 * 32 + col] : 0.f;
        float v1 = (k0 + 1 < 36) ? W[(size_t)(k0 + 1) * 32 + col] : 0.f;
        if (hl) {
            v0 -= bf2f(bf_rne1(v0));
            v1 -= bf2f(bf_rne1(v1));
        }
        o[i] = bfpair(v0, v1);
    }
    frag[idx] = o;
}

// ---------------- fused layer: pipelined MFMA edge GEMM + b128 segsum + node update ----------------
__global__ __launch_bounds__(256) void layer_kernel(const float* __restrict__ h,
                                                    const uint32_t* __restrict__ h_hi,
                                                    const uint32_t* __restrict__ h_lo,
                                                    const u32x4* __restrict__ ef4,
                                                    const uint2* __restrict__ se,
                                                    const int* __restrict__ row_ptr,
                                                    const float* __restrict__ rain0,
                                                    const u32x4* __restrict__ wfrag,
                                                    const float* __restrict__ Wn,
                                                    const float* __restrict__ Wrain,
                                                    float* __restrict__ hnew,
                                                    uint32_t* __restrict__ hn_hi,
                                                    uint32_t* __restrict__ hn_lo,
                                                    float* __restrict__ out,
                                                    int t, int last) {
    __shared__ float msg[CHUNK * 36];   // [edge-in-chunk][ch], pad 36 -> b128 segsum reads
    __shared__ float shl[NPB * 33];
    __shared__ float sagg[NPB * 33];
    __shared__ float srain[NPB];
    __shared__ int srp[NPB + 1];

    int tid = threadIdx.x;
    int nb0 = blockIdx.x * NPB;
    int nEnd = min(nb0 + NPB, NN);
    int nloc = nEnd - nb0;

    if (tid <= nloc) srp[tid] = row_ptr[nb0 + tid];
    for (int i = tid; i < nloc * 32; i += 256) {
        int g = i >> 5, c = i & 31;
        shl[g * 33 + c] = h[(size_t)(nb0 + g) * 32 + c];
    }
    if (tid < NPB) srain[tid] = 0.f;
    __syncthreads();
    int e0 = srp[0], e1 = srp[nloc];

    int lane = tid & 63, w = tid >> 6;
    int l15 = lane & 15, kg = lane >> 4;

    // hoist B fragments into registers
    u32x4 b[2][2][2];
#pragma unroll
    for (int ks = 0; ks < 2; ++ks)
#pragma unroll
        for (int nt = 0; nt < 2; ++nt)
#pragma unroll
            for (int hl = 0; hl < 2; ++hl)
                b[ks][nt][hl] = wfrag[((ks * 2 + nt) * 2 + hl) * 64 + lane];

    // segsum ownership: thread (sg, sl) -> node sg, channels sl*4..+3
    int sg = tid >> 3, sl = tid & 7;
    int arb = (sg < nloc) ? srp[sg] : 0;
    int are = (sg < nloc) ? srp[sg + 1] : 0;
    float4 aggv = make_float4(0.f, 0.f, 0.f, 0.f);

    struct Frag { u32x4 ah, al, e4; };

    auto loadS = [&](int gs) -> int {
        int p = e0 + gs * 64 + w * 16 + l15;
        int pc = p < e1 ? p : e1 - 1;
        return (int)se[pc].x;
    };
    auto loadFrag = [&](int s, int gs) -> Frag {
        Frag f;
        const uint2* hh = (const uint2*)h_hi + (size_t)s * 8;
        const uint2* hl = (const uint2*)h_lo + (size_t)s * 8;
        uint2 A0 = hh[kg], A1 = hh[4 + kg];
        uint2 L0 = hl[kg], L1 = hl[4 + kg];
        f.ah = u32x4{A0.x, A0.y, A1.x, A1.y};
        f.al = u32x4{L0.x, L0.y, L1.x, L1.y};
        if (kg == 0) {
            int p = e0 + gs * 64 + w * 16 + l15;
            int pc = p < e1 ? p : e1 - 1;
            f.e4 = ef4[pc];
        } else {
            f.e4 = u32x4{0u, 0u, 0u, 0u};
        }
        return f;
    };
    auto compute = [&](Frag f, int rowbase) {
        u32x4 a1h = {f.e4[0], f.e4[1], 0u, 0u};
        u32x4 a1l = {f.e4[2], f.e4[3], 0u, 0u};
        f32x4 c0 = {0.f, 0.f, 0.f, 0.f};
        f32x4 c1 = {0.f, 0.f, 0.f, 0.f};
        bf16x8 Ah = asbf(f.ah), Al = asbf(f.al), Eh = asbf(a1h), El = asbf(a1l);
        c0 = MFMA(Ah, asbf(b[0][0][0]), c0);
        c0 = MFMA(Ah, asbf(b[0][0][1]), c0);
        c0 = MFMA(Al, asbf(b[0][0][0]), c0);
        c0 = MFMA(Eh, asbf(b[1][0][0]), c0);
        c0 = MFMA(Eh, asbf(b[1][0][1]), c0);
        c0 = MFMA(El, asbf(b[1][0][0]), c0);
        c1 = MFMA(Ah, asbf(b[0][1][0]), c1);
        c1 = MFMA(Ah, asbf(b[0][1][1]), c1);
        c1 = MFMA(Al, asbf(b[0][1][0]), c1);
        c1 = MFMA(Eh, asbf(b[1][1][0]), c1);
        c1 = MFMA(Eh, asbf(b[1][1][1]), c1);
        c1 = MFMA(El, asbf(b[1][1][0]), c1);
        // C/D: col(channel) = lane&15, row(edge) = kg*4 + reg  [r7-verified end-to-end]
        int rb = rowbase + kg * 4;
#pragma unroll
        for (int r = 0; r < 4; ++r) {
            msg[(rb + r) * 36 + l15] = fmaxf(c0[r], 0.f);
            msg[(rb + r) * 36 + 16 + l15] = fmaxf(c1[r], 0.f);
        }
    };

    if (e0 < e1) {
        int nch = (e1 - e0 + CHUNK - 1) / CHUNK;
        // bootstrap pipeline: s for subs 0..3, frags for subs 0,1
        int sE = loadS(0), sO = loadS(1);
        Frag fE = loadFrag(sE, 0);
        Frag fO = loadFrag(sO, 1);
        sE = loadS(2); sO = loadS(3);

#define SUB_BODY(FSLOT, SSLOT, GS)                         \
        {                                                  \
            Frag fNew = loadFrag(SSLOT, (GS) + 2);         \
            int sNew = loadS((GS) + 4);                    \
            compute(FSLOT, (((GS) & 3) * 64 + w * 16));    \
            FSLOT = fNew; SSLOT = sNew;                    \
        }

#pragma unroll 1
        for (int c = 0; c < nch; ++c) {
            int g0 = c * 4;
            SUB_BODY(fE, sE, g0 + 0)
            SUB_BODY(fO, sO, g0 + 1)
            SUB_BODY(fE, sE, g0 + 2)
            SUB_BODY(fO, sO, g0 + 3)
            __syncthreads();
            int cb = e0 + c * CHUNK;
            if (sg < nloc) {
                int lo = max(arb, cb), hi2 = min(are, cb + CHUNK);
                for (int p2 = lo; p2 < hi2; ++p2) {
                    float4 v = *(const float4*)&msg[(p2 - cb) * 36 + sl * 4];
                    aggv.x += v.x; aggv.y += v.y; aggv.z += v.z; aggv.w += v.w;
                }
            }
            __syncthreads();
        }
#undef SUB_BODY
    }
    if (sg < nloc) {
        sagg[sg * 33 + sl * 4 + 0] = aggv.x;
        sagg[sg * 33 + sl * 4 + 1] = aggv.y;
        sagg[sg * 33 + sl * 4 + 2] = aggv.z;
        sagg[sg * 33 + sl * 4 + 3] = aggv.w;
    }
    __syncthreads();

    // ---- node phase: thread (nl, cq) -> node nl, channels cq*4..+3 (exclusive) ----
    int nl = tid >> 3, cq = tid & 7;
    if (nl < nloc) {
        int n = nb0 + nl;
        float4 a = make_float4(0.f, 0.f, 0.f, 0.f);
#pragma unroll 8
        for (int k = 0; k < 32; ++k) {
            float xk = shl[nl * 33 + k];
            float4 wv = *(const float4*)(Wn + (size_t)k * 32 + cq * 4);
            a.x = fmaf(xk, wv.x, a.x); a.y = fmaf(xk, wv.y, a.y);
            a.z = fmaf(xk, wv.z, a.z); a.w = fmaf(xk, wv.w, a.w);
        }
#pragma unroll 8
        for (int k = 0; k < 32; ++k) {
            float xk = sagg[nl * 33 + k];
            float4 wv = *(const float4*)(Wn + (size_t)(32 + k) * 32 + cq * 4);
            a.x = fmaf(xk, wv.x, a.x); a.y = fmaf(xk, wv.y, a.y);
            a.z = fmaf(xk, wv.z, a.z); a.w = fmaf(xk, wv.w, a.w);
        }
        {
            float rain = rain0[(size_t)n * T_STEPS + t];
            float4 wv = *(const float4*)(Wn + (size_t)64 * 32 + cq * 4);
            a.x = fmaf(rain, wv.x, a.x); a.y = fmaf(rain, wv.y, a.y);
            a.z = fmaf(rain, wv.z, a.z); a.w = fmaf(rain, wv.w, a.w);
        }
        a.x = fmaxf(a.x, 0.f); a.y = fmaxf(a.y, 0.f);
        a.z = fmaxf(a.z, 0.f); a.w = fmaxf(a.w, 0.f);
        *(float4*)(hnew + (size_t)n * 32 + cq * 4) = a;
        uint32_t p0 = bfpair(a.x, a.y), p1 = bfpair(a.z, a.w);
        hn_hi[(size_t)n * 16 + cq * 2] = p0;
        hn_hi[(size_t)n * 16 + cq * 2 + 1] = p1;
        float r0 = a.x - bf2f(p0 & 0xFFFFu), r1 = a.y - bf2f(p0 >> 16);
        float r2 = a.z - bf2f(p1 & 0xFFFFu), r3 = a.w - bf2f(p1 >> 16);
        hn_lo[(size_t)n * 16 + cq * 2] = bfpair(r0, r1);
        hn_lo[(size_t)n * 16 + cq * 2 + 1] = bfpair(r2, r3);
        if (last) {
            float4 wr = *(const float4*)(Wrain + cq * 4);
            float rv = a.x * wr.x + a.y * wr.y + a.z * wr.z + a.w * wr.w;
            atomicAdd(&srain[nl], rv);
        }
    }
    if (last) {
        __syncthreads();
        if (tid < nloc) out[(size_t)(nb0 + tid) * T_STEPS + t] = srain[tid];
    }
}

extern "C" void kernel_launch(void* const* d_in, const int* in_sizes, int n_in,
                              void* d_out, int out_size, void* d_ws, size_t ws_size,
                              hipStream_t stream) {
    const float* inputs     = (const float*)d_in[0];
    const float* e_feats    = (const float*)d_in[1];
    const float* rain0      = (const float*)d_in[2];
    const float* W_emb      = (const float*)d_in[3];
    const float* W_edge_in  = (const float*)d_in[4];
    const float* W_node_in  = (const float*)d_in[5];
    const float* W_edge_out = (const float*)d_in[6];
    const float* W_node_out = (const float*)d_in[7];
    const float* W_rain     = (const float*)d_in[8];
    const int*   src        = (const int*)d_in[9];
    const int*   dst        = (const int*)d_in[10];
    float* out = (float*)d_out;

    // workspace layout (~84 MB)
    float* h_a = (float*)d_ws;                                   // NN*32
    float* h_b = h_a + (size_t)NN * 32;                          // NN*32
    uint32_t* hhi_a = (uint32_t*)(h_b + (size_t)NN * 32);        // NN*16
    uint32_t* hlo_a = hhi_a + (size_t)NN * 16;
    uint32_t* hhi_b = hlo_a + (size_t)NN * 16;
    uint32_t* hlo_b = hhi_b + (size_t)NN * 16;
    u32x4* ef4      = (u32x4*)(hlo_b + (size_t)NN * 16);         // T*NE u32x4
    u32x4* wfrag    = ef4 + (size_t)T_STEPS * NE;                // 1536
    int* row_ptr    = (int*)(wfrag + 1536);                      // NN+1
    int* deg        = row_ptr + (NN + 1);                        // NN
    int* cnt        = deg + NN;                                  // NN
    uint2* se       = (uint2*)(cnt + NN + 1);                    // NE (8B aligned)
    int* bsum       = (int*)(se + NE);                           // SBLK
    int* btop       = bsum + SBLK;                               // SBLK

    embed_kernel<<<(NN * 8 + 255) / 256, 256, 0, stream>>>(inputs, W_emb, h_a, hhi_a, hlo_a);

    // CSR build (hierarchical scan)
    hipMemsetAsync(deg, 0, (size_t)2 * NN * sizeof(int), stream);  // deg + cnt contiguous
    hist_kernel<<<(NE + 255) / 256, 256, 0, stream>>>(dst, deg);
    scan_part<<<SBLK, 256, 0, stream>>>(deg, bsum);
    scan_tops<<<1, 256, 0, stream>>>(bsum, btop);
    scan_final<<<SBLK, 256, 0, stream>>>(deg, btop, row_ptr);
    scatter_kernel<<<(NE + 255) / 256, 256, 0, stream>>>(src, dst, row_ptr, cnt, se);
    ef_sort_kernel<<<(NE + 255) / 256, 256, 0, stream>>>(e_feats, se, ef4);
    wefrag_kernel<<<6, 256, 0, stream>>>(W_edge_in, W_edge_out, wfrag);

    float* hc = h_a;  float* hn = h_b;
    uint32_t* hic = hhi_a; uint32_t* hil = hlo_a;
    uint32_t* hnc = hhi_b; uint32_t* hnl = hlo_b;
    for (int t = 0; t < T_STEPS; ++t) {
        const u32x4* ef4_t = ef4 + (size_t)t * NE;
        for (int s = 0; s < 3; ++s) {
            int mat = (s < 2) ? s : 2;
            const float* Wn = (s < 2) ? (W_node_in + (size_t)s * 65 * 32) : W_node_out;
            layer_kernel<<<NBLK, 256, 0, stream>>>(hc, hic, hil, ef4_t, se, row_ptr, rain0,
                                                   wfrag + (size_t)mat * 512, Wn, W_rain,
                                                   hn, hnc, hnl, out, t, (s == 2) ? 1 : 0);
            float* tf = hc; hc = hn; hn = tf;
            uint32_t* t1 = hic; hic = hnc; hnc = t1;
            uint32_t* t2 = hil; hil = hnl; hnl = t2;
        }
    }
}